// Round 10
// baseline (124.943 us; speedup 1.0000x reference)
//
#include <hip/hip_runtime.h>

#define BB 2
#define NN 768
#define FF 128
#define HH 128
#define TS 32
#define LST 68                       // LDS row stride (floats): 272B rows, 16B-aligned, <=2-way banks
#define NT (NN / TS)                 // 24 tiles per dim
#define NPAIR (NT * (NT + 1) / 2)    // 300 upper-triangular tile pairs
#define EROWS 2
#define THR 4e-3f
#define NBIN 8192
#define PIf 3.14159265358979323846f

// ---- exact f64 slow path: recompute gram from global Xc + f64 MLP --------
// Same math as the always-f64 baseline; executed only in a cold branch
// (|m32| < THR or multi-breakpoint LUT bin, ~1e-4 of edges).
__device__ __forceinline__
double edge_exact_f64(const double* __restrict__ Xc, const double* __restrict__ wpack,
                      int b, int i, int j, double init) {
    const double* xi0 = Xc + ((size_t)(b * 2 + 0) * NN + i) * 64;
    const double* xj0 = Xc + ((size_t)(b * 2 + 0) * NN + j) * 64;
    const double* xi1 = Xc + ((size_t)(b * 2 + 1) * NN + i) * 64;
    const double* xj1 = Xc + ((size_t)(b * 2 + 1) * NN + j) * 64;
    double p0 = 0.0, p1 = 0.0;
#pragma unroll 4
    for (int d2 = 0; d2 < 32; ++d2) {
        double2 a0 = *(const double2*)&xi0[2 * d2];
        double2 b0 = *(const double2*)&xj0[2 * d2];
        double2 a1 = *(const double2*)&xi1[2 * d2];
        double2 b1 = *(const double2*)&xj1[2 * d2];
        p0 = fma(a0.y, b0.y, fma(a0.x, b0.x, p0));
        p1 = fma(a1.y, b1.y, fma(a1.x, b1.x, p1));
    }
    double m = init;
#pragma unroll 8
    for (int c = 0; c < HH; ++c) {
        double2 wab = *(const double2*)&wpack[4 * c];        // a, b
        double2 wbw = *(const double2*)&wpack[4 * c + 2];    // beta, wd
        double tt = fma(p1, wab.y, fma(p0, wab.x, wbw.x));
        tt = fmax(tt, 0.0);
        m = fma(tt, wbw.y, m);
    }
    return m;
}

// k1: feats = relu(X@w1+b1)@w2+b2 (f64 accum, split-K x2); Xc (f64) + Xcf (f32).
// Block 0 packs score-MLP weights. Blocks 0..31 additionally build the angular
// LUT (one bin per thread, no sort): per bin, {A,B} of the sector at the bin's
// left edge + the single in-bin breakpoint's oriented (xa,xb,wd). Bins with >=2
// breakpoints are flagged (exact-f64 at eval). Zero-bias only; flagp gates it.
__global__ __launch_bounds__(256)
void edgefeat_kernel(const float* __restrict__ X,
                     const float* __restrict__ w1, const float* __restrict__ b1,
                     const float* __restrict__ w2, const float* __restrict__ b2,
                     const float* __restrict__ gatep,
                     const float* __restrict__ sm_w1, const float* __restrict__ sm_b1,
                     const float* __restrict__ sm_w2,
                     double* __restrict__ Xc, float* __restrict__ Xcf,
                     double* __restrict__ wpack, float4* __restrict__ wpackf,
                     float4* __restrict__ tab, float* __restrict__ flagp) {
    __shared__ float  Xs[EROWS][FF];
    __shared__ double Hp[2][EROWS][HH];   // per-K-half partials (reused for layer 2)
    __shared__ double Hs[EROWS][HH];      // relu'd hidden
    const int tid = threadIdx.x;
    const int h  = tid & 127;             // output column
    const int kh = tid >> 7;              // K-half 0/1
    const int row0 = blockIdx.x * EROWS;  // global row in [0, B*N)
    Xs[kh][h] = X[(size_t)(row0 + kh) * FF + h];   // 256 threads stage 2 rows
    if (blockIdx.x == 0 && kh == 0) {
        // wpack[c] = {w1[0,c], w1[1,c], b1[c], w2[c,1]-w2[c,0]}
        double a  = (double)sm_w1[h];
        double bq = (double)sm_w1[HH + h];
        double be = (double)sm_b1[h];
        double wd = (double)sm_w2[2 * h + 1] - (double)sm_w2[2 * h + 0];
        wpack[4 * h + 0] = a;  wpack[4 * h + 1] = bq;
        wpack[4 * h + 2] = be; wpack[4 * h + 3] = wd;
        wpackf[h] = make_float4((float)a, (float)bq, (float)be, (float)wd);
    }
    __syncthreads();
    const int f0 = kh * 64;
    // layer 1, K-half kh
    double acc0 = (kh == 0) ? (double)b1[h] : 0.0;
    double acc1 = acc0;
    for (int f = f0; f < f0 + 64; ++f) {
        double w = (double)w1[f * HH + h];        // coalesced across h
        acc0 = fma((double)Xs[0][f], w, acc0);
        acc1 = fma((double)Xs[1][f], w, acc1);
    }
    Hp[kh][0][h] = acc0; Hp[kh][1][h] = acc1;
    __syncthreads();
    if (kh == 0) {
        double v0 = Hp[0][0][h] + Hp[1][0][h];
        double v1 = Hp[0][1][h] + Hp[1][1][h];
        Hs[0][h] = v0 > 0.0 ? v0 : 0.0;
        Hs[1][h] = v1 > 0.0 ? v1 : 0.0;
    }
    __syncthreads();
    // layer 2, K-half kh
    acc0 = (kh == 0) ? (double)b2[h] : 0.0;
    acc1 = acc0;
    for (int c = f0; c < f0 + 64; ++c) {
        double w = (double)w2[c * HH + h];
        acc0 = fma(Hs[0][c], w, acc0);
        acc1 = fma(Hs[1][c], w, acc1);
    }
    Hp[kh][0][h] = acc0; Hp[kh][1][h] = acc1;
    __syncthreads();
    if (kh == 0) {
        const double gate = (double)gatep[0];
        const int k = h & 1, d = h >> 1;
        const int b = row0 / NN;
        const int i0 = row0 % NN;
#pragma unroll
        for (int r = 0; r < EROWS; ++r) {
            double a = Hp[0][r][h] + Hp[1][r][h];
            double v = (double)Xs[r][h] + gate * a;
            size_t idx = (((size_t)(b * 2 + k)) * NN + (i0 + r)) * 64 + d;
            Xc[idx]  = v;
            Xcf[idx] = (float)v;
        }
    }

    // ---- angular LUT build: bin = global thread id (blocks 0..31) ----------
    const int bin = blockIdx.x * 256 + tid;
    if (bin < NBIN) {
        const float D = 2.f * PIf / (float)NBIN;
        float thL = -PIf + (float)bin * D, thR = thL + D;
        float sL, cL, sR, cR;
        sincosf(thL, &sL, &cL);
        sincosf(thR, &sR, &cR);
        float A = 0.f, Bv = 0.f, xa = 0.f, xb = 0.f, xw = 0.f;
        int ncr = 0;
#pragma unroll 8
        for (int c = 0; c < HH; ++c) {
            float a  = sm_w1[c], bq = sm_w1[HH + c];
            float wd = sm_w2[2 * c + 1] - sm_w2[2 * c];
            float hL = fmaf(a, cL, bq * sL);
            float hR = fmaf(a, cR, bq * sR);
            bool actL = hL > 0.f;
            if (actL) { A = fmaf(wd, a, A); Bv = fmaf(wd, bq, Bv); }
            if (actL != (hR > 0.f)) {
                ++ncr;
                float sg = actL ? -1.f : 1.f;   // falling: negate so corr = wd*max(-h,0)
                xa = sg * a; xb = sg * bq; xw = wd;
            }
        }
        tab[2 * bin]     = make_float4(A, Bv, xa, xb);
        tab[2 * bin + 1] = make_float4(xw, (ncr >= 2) ? 1.f : 0.f, 0.f, 0.f);
        if (bin == 0) {
            float fl = 0.f;
            for (int c = 0; c < HH; ++c) if (sm_b1[c] != 0.f) fl = 1.f;
            flagp[0] = fl;
        }
    }
}

// k2: 512 threads per 32x32 tile. Lane-pair slicing (s = tid&1) on the gram
// K-dim (b128 LDS reads, __shfl_xor reduce); per-edge margin via the angular
// LUT (exact within single-breakpoint bins); multi-breakpoint bins and
// |m| < THR re-decided exactly in f64. Biased weights fall back to f32 MLP.
__global__ __launch_bounds__(512, 6)
void edge_decide_kernel(const double* __restrict__ Xc,
                        const float* __restrict__ Xcf,
                        const double* __restrict__ wpack,
                        const float4* __restrict__ wpackf,
                        const float4* __restrict__ tab, const float* __restrict__ flagp,
                        const float* __restrict__ sm_b2,
                        const float* __restrict__ gumbel,
                        float* __restrict__ out) {
    __shared__ float  Ai[2][TS][LST];  // 272B rows: 16B-aligned, banks <=2-way (free)
    __shared__ float  Aj[2][TS][LST];
    __shared__ float  As[TS][TS + 1];
    const int b = blockIdx.y;
    const int t = blockIdx.x;
    // decode upper-triangular pair index: t -> (ti, tj), tj >= ti   (T=24)
    int ti = (int)((49.0 - sqrt(2401.0 - 8.0 * (double)t)) * 0.5);
    int base = ti * (49 - ti) / 2;
    if (t < base) { --ti; base = ti * (49 - ti) / 2; }
    else { int nb = (ti + 1) * (48 - ti) / 2; if (t >= nb) { ++ti; base = nb; } }
    const int tj = t - base + ti;
    const int tid = threadIdx.x;
    const int i0 = ti * TS, j0 = tj * TS;

    // stage f32 Xcf tiles (coalesced float4 global reads; 4 loads/thread)
    for (int q = 0; q < 2; ++q) {
        int flat = tid + 512 * q;        // index over (k, r, d4)
        int d4 = flat & 15;              // float4 slot within row (16/row)
        int r  = (flat >> 4) & 31;
        int k  = flat >> 9;
        size_t rowbase = ((size_t)(b * 2 + k)) * NN;
        *(float4*)&Ai[k][r][4 * d4] = *(const float4*)&Xcf[(rowbase + i0 + r) * 64 + 4 * d4];
        *(float4*)&Aj[k][r][4 * d4] = *(const float4*)&Xcf[(rowbase + j0 + r) * 64 + 4 * d4];
    }

    const int s  = tid & 1;          // slice within lane pair
    const int e  = tid >> 1;         // edge-quad id 0..255
    const int rh = e >> 4;           // 0..15
    const int ch = e & 15;           // 0..15
    const int r0 = rh, r1 = rh + 16;
    const int c0 = 2 * ch, c1 = c0 + 1;
    const int lr  = (s == 0) ? r0 : r1;     // lane-owned local row
    const int gr  = i0 + lr;                // lane-owned global row
    const int gj0 = j0 + c0, gj1 = j0 + c1;

    // per-lane gumbel load for the owned row (issued early, hidden under gram)
    float4 gv = *(const float4*)&gumbel[(((size_t)b * NN + gr) * NN + gj0) * 2];
    const float biased = flagp[0];
    __syncthreads();

    // f32 gram, K-sliced via b128 reads: slice s covers float4 idx s+2*it
    float p000 = 0.f, p001 = 0.f, p010 = 0.f, p011 = 0.f;
    float p100 = 0.f, p101 = 0.f, p110 = 0.f, p111 = 0.f;
#pragma unroll
    for (int it = 0; it < 8; ++it) {
        const int d4 = (s + 2 * it) * 4;    // float offset of the float4
        float4 a00 = *(const float4*)&Ai[0][r0][d4];
        float4 a01 = *(const float4*)&Ai[0][r1][d4];
        float4 a10 = *(const float4*)&Ai[1][r0][d4];
        float4 a11 = *(const float4*)&Ai[1][r1][d4];
        float4 b00 = *(const float4*)&Aj[0][c0][d4];
        float4 b01 = *(const float4*)&Aj[0][c1][d4];
        float4 b10 = *(const float4*)&Aj[1][c0][d4];
        float4 b11 = *(const float4*)&Aj[1][c1][d4];
        p000 = fmaf(a00.w, b00.w, fmaf(a00.z, b00.z, fmaf(a00.y, b00.y, fmaf(a00.x, b00.x, p000))));
        p001 = fmaf(a00.w, b01.w, fmaf(a00.z, b01.z, fmaf(a00.y, b01.y, fmaf(a00.x, b01.x, p001))));
        p010 = fmaf(a01.w, b00.w, fmaf(a01.z, b00.z, fmaf(a01.y, b00.y, fmaf(a01.x, b00.x, p010))));
        p011 = fmaf(a01.w, b01.w, fmaf(a01.z, b01.z, fmaf(a01.y, b01.y, fmaf(a01.x, b01.x, p011))));
        p100 = fmaf(a10.w, b10.w, fmaf(a10.z, b10.z, fmaf(a10.y, b10.y, fmaf(a10.x, b10.x, p100))));
        p101 = fmaf(a10.w, b11.w, fmaf(a10.z, b11.z, fmaf(a10.y, b11.y, fmaf(a10.x, b11.x, p101))));
        p110 = fmaf(a11.w, b10.w, fmaf(a11.z, b10.z, fmaf(a11.y, b10.y, fmaf(a11.x, b10.x, p110))));
        p111 = fmaf(a11.w, b11.w, fmaf(a11.z, b11.z, fmaf(a11.y, b11.y, fmaf(a11.x, b11.x, p111))));
    }
    // butterfly-reduce p over the lane pair; both lanes get the full dots
    p000 += __shfl_xor(p000, 1); p001 += __shfl_xor(p001, 1);
    p010 += __shfl_xor(p010, 1); p011 += __shfl_xor(p011, 1);
    p100 += __shfl_xor(p100, 1); p101 += __shfl_xor(p101, 1);
    p110 += __shfl_xor(p110, 1); p111 += __shfl_xor(p111, 1);

    // lane-owned edges: (lr, c0) and (lr, c1)
    const float pa0 = (s == 0) ? p000 : p010;   // k0, col c0
    const float pa1 = (s == 0) ? p100 : p110;   // k1, col c0
    const float pb0 = (s == 0) ? p001 : p011;   // k0, col c1
    const float pb1 = (s == 0) ? p101 : p111;   // k1, col c1

    float ma, mb;
    bool xfa = false, xfb = false;   // force exact-f64 (multi-breakpoint bin)
    if (biased == 0.f) {
        // angular LUT: m = A*p0 + B*p1 + wd*max(xa*p0 + xb*p1, 0) — exact
        // within single-breakpoint bins (piecewise-linear homogeneous f).
        const float BS = (float)NBIN / (2.f * PIf);
        float tha = atan2f(pa1, pa0);
        float thb = atan2f(pb1, pb0);
        int bina = (int)fminf(fmaxf((tha + PIf) * BS, 0.f), (float)(NBIN - 1));
        int binb = (int)fminf(fmaxf((thb + PIf) * BS, 0.f), (float)(NBIN - 1));
        float4 ta0 = tab[2 * bina], ta1 = tab[2 * bina + 1];
        float4 tb0 = tab[2 * binb], tb1 = tab[2 * binb + 1];
        ma = fmaf(ta0.x, pa0, ta0.y * pa1) + ta1.x * fmaxf(fmaf(ta0.z, pa0, ta0.w * pa1), 0.f);
        mb = fmaf(tb0.x, pb0, tb0.y * pb1) + tb1.x * fmaxf(fmaf(tb0.z, pb0, tb0.w * pb1), 0.f);
        xfa = (ta1.y != 0.f);
        xfb = (tb1.y != 0.f);
    } else {
        // general-bias fallback: full f32 MLP, batched uniform scalar loads
        ma = 0.f; mb = 0.f;
#pragma unroll 1
        for (int c = 0; c < HH; c += 8) {
            float4 w[8];
#pragma unroll
            for (int u = 0; u < 8; ++u) w[u] = wpackf[c + u];
#pragma unroll
            for (int u = 0; u < 8; ++u) {
                float tt;
                tt = fmaf(pa1, w[u].y, fmaf(pa0, w[u].x, w[u].z)); tt = fmaxf(tt, 0.f); ma = fmaf(tt, w[u].w, ma);
                tt = fmaf(pb1, w[u].y, fmaf(pb0, w[u].x, w[u].z)); tt = fmaxf(tt, 0.f); mb = fmaf(tt, w[u].w, mb);
            }
        }
    }

    // decision per lane (2 edges), rare exact-f64 re-decide
    const double bd = (double)sm_b2[1] - (double)sm_b2[0];
    double ia = bd + ((double)gv.y - (double)gv.x);
    double ib = bd + ((double)gv.w - (double)gv.z);
    float fa = ma + (float)ia;
    float fb = mb + (float)ib;
    float Aa = fa > 0.f ? 1.f : 0.f;
    float Ab = fb > 0.f ? 1.f : 0.f;
    if (__builtin_expect(xfa || xfb || fminf(fabsf(fa), fabsf(fb)) < THR, 0)) {
        if (xfa || fabsf(fa) < THR) Aa = edge_exact_f64(Xc, wpack, b, gr, gj0, ia) > 0.0 ? 1.f : 0.f;
        if (xfb || fabsf(fb) < THR) Ab = edge_exact_f64(Xc, wpack, b, gr, gj1, ib) > 0.0 ? 1.f : 0.f;
    }
    As[lr][c0] = Aa; As[lr][c1] = Ab;
    __syncthreads();

    if (ti != tj) {
        // direct tile: each lane writes its own row pair (i<j guaranteed)
        *(float2*)&out[((size_t)b * NN + gr) * NN + gj0] = make_float2(Aa, Ab);
        // transposed tile: row j0+lr, cols i0+c0..c1
        float2 tv = make_float2(As[c0][lr], As[c1][lr]);
        *(float2*)&out[((size_t)b * NN + j0 + lr) * NN + i0 + c0] = tv;
    } else {
        // diagonal tile: upper value mirrored, diag = 0
        float v0 = (lr < c0) ? Aa : ((lr > c0) ? As[c0][lr] : 0.0f);
        float v1 = (lr < c1) ? Ab : ((lr > c1) ? As[c1][lr] : 0.0f);
        *(float2*)&out[((size_t)b * NN + gr) * NN + gj0] = make_float2(v0, v1);
    }
}

extern "C" void kernel_launch(void* const* d_in, const int* in_sizes, int n_in,
                              void* d_out, int out_size, void* d_ws, size_t ws_size,
                              hipStream_t stream) {
    const float* X      = (const float*)d_in[0];
    const float* ef_w1  = (const float*)d_in[1];
    const float* ef_b1  = (const float*)d_in[2];
    const float* ef_w2  = (const float*)d_in[3];
    const float* ef_b2  = (const float*)d_in[4];
    const float* gate   = (const float*)d_in[5];
    const float* sm_w1  = (const float*)d_in[6];
    const float* sm_b1  = (const float*)d_in[7];
    const float* sm_w2  = (const float*)d_in[8];
    const float* sm_b2  = (const float*)d_in[9];
    const float* gumbel = (const float*)d_in[10];
    float* out = (float*)d_out;

    double* Xc     = (double*)d_ws;                         // 2*2*768*64 doubles = 1.5 MiB
    double* wpack  = Xc + (size_t)BB * 2 * NN * 64;         // 512 doubles
    float4* wpackf = (float4*)(wpack + 4 * HH);             // 128 float4
    float*  Xcf    = (float*)(wpackf + HH);                 // 768 KiB f32 copy
    float4* tab    = (float4*)(Xcf + (size_t)BB * 2 * NN * 64);  // 16384 float4 = 256 KiB
    float*  flagp  = (float*)(tab + 2 * NBIN);              // 1 float

    edgefeat_kernel<<<BB * NN / EROWS, 256, 0, stream>>>(
        X, ef_w1, ef_b1, ef_w2, ef_b2, gate, sm_w1, sm_b1, sm_w2,
        Xc, Xcf, wpack, wpackf, tab, flagp);
    dim3 grid(NPAIR, BB);
    edge_decide_kernel<<<grid, 512, 0, stream>>>(
        Xc, Xcf, wpack, wpackf, tab, flagp, sm_b2, gumbel, out);
}

// Round 11
// 116.371 us; speedup vs baseline: 1.0737x; 1.0737x over previous
//
#include <hip/hip_runtime.h>

#define BB 2
#define NN 768
#define FF 128
#define HH 128
#define TS 32
#define LST 68                       // LDS row stride (floats): 272B rows, 16B-aligned, <=2-way banks
#define NT (NN / TS)                 // 24 tiles per dim
#define NPAIR (NT * (NT + 1) / 2)    // 300 upper-triangular tile pairs
#define EROWS 2
#define THR 4e-3f

typedef float v2f __attribute__((ext_vector_type(2)));

// ---- exact f64 slow path: recompute gram from global Xc + f64 MLP --------
// Same math as the always-f64 baseline; executed only in a cold branch
// (|m32| < THR, ~1e-4 of edges). Fully inlined: no call ABI/spills.
__device__ __forceinline__
double edge_exact_f64(const double* __restrict__ Xc, const double* __restrict__ wpack,
                      int b, int i, int j, double init) {
    const double* xi0 = Xc + ((size_t)(b * 2 + 0) * NN + i) * 64;
    const double* xj0 = Xc + ((size_t)(b * 2 + 0) * NN + j) * 64;
    const double* xi1 = Xc + ((size_t)(b * 2 + 1) * NN + i) * 64;
    const double* xj1 = Xc + ((size_t)(b * 2 + 1) * NN + j) * 64;
    double p0 = 0.0, p1 = 0.0;
#pragma unroll 4
    for (int d2 = 0; d2 < 32; ++d2) {
        double2 a0 = *(const double2*)&xi0[2 * d2];
        double2 b0 = *(const double2*)&xj0[2 * d2];
        double2 a1 = *(const double2*)&xi1[2 * d2];
        double2 b1 = *(const double2*)&xj1[2 * d2];
        p0 = fma(a0.y, b0.y, fma(a0.x, b0.x, p0));
        p1 = fma(a1.y, b1.y, fma(a1.x, b1.x, p1));
    }
    double m = init;
#pragma unroll 8
    for (int c = 0; c < HH; ++c) {
        double2 wab = *(const double2*)&wpack[4 * c];        // a, b
        double2 wbw = *(const double2*)&wpack[4 * c + 2];    // beta, wd
        double tt = fma(p1, wab.y, fma(p0, wab.x, wbw.x));
        tt = fmax(tt, 0.0);
        m = fma(tt, wbw.y, m);
    }
    return m;
}

// k1: feats = relu(X@w1+b1)@w2+b2 (f64 accum, split-K x2); Xc (f64) + Xcf (f32).
// Block 0 packs score-MLP weights: wpack (f64 AoS), and wq2 (channel-PAIR SoA
// float2 quads {a,a'},{b,b'},{beta,beta'},{wd,wd'} for packed-f32 MLP in k2).
__global__ __launch_bounds__(256)
void edgefeat_kernel(const float* __restrict__ X,
                     const float* __restrict__ w1, const float* __restrict__ b1,
                     const float* __restrict__ w2, const float* __restrict__ b2,
                     const float* __restrict__ gatep,
                     const float* __restrict__ sm_w1, const float* __restrict__ sm_b1,
                     const float* __restrict__ sm_w2,
                     double* __restrict__ Xc, float* __restrict__ Xcf,
                     double* __restrict__ wpack, float2* __restrict__ wq2) {
    __shared__ float  Xs[EROWS][FF];
    __shared__ double Hp[2][EROWS][HH];   // per-K-half partials (reused for layer 2)
    __shared__ double Hs[EROWS][HH];      // relu'd hidden
    const int tid = threadIdx.x;
    const int h  = tid & 127;             // output column
    const int kh = tid >> 7;              // K-half 0/1
    const int row0 = blockIdx.x * EROWS;  // global row in [0, B*N)
    Xs[kh][h] = X[(size_t)(row0 + kh) * FF + h];   // 256 threads stage 2 rows
    if (blockIdx.x == 0 && kh == 0) {
        // wpack[c] = {w1[0,c], w1[1,c], b1[c], w2[c,1]-w2[c,0]}
        double a  = (double)sm_w1[h];
        double bq = (double)sm_w1[HH + h];
        double be = (double)sm_b1[h];
        double wd = (double)sm_w2[2 * h + 1] - (double)sm_w2[2 * h + 0];
        wpack[4 * h + 0] = a;  wpack[4 * h + 1] = bq;
        wpack[4 * h + 2] = be; wpack[4 * h + 3] = wd;
        if (h < 64) {   // channel-pair SoA quads for the packed MLP
            int ca = 2 * h, cb = 2 * h + 1;
            wq2[4 * h + 0] = make_float2(sm_w1[ca], sm_w1[cb]);
            wq2[4 * h + 1] = make_float2(sm_w1[HH + ca], sm_w1[HH + cb]);
            wq2[4 * h + 2] = make_float2(sm_b1[ca], sm_b1[cb]);
            wq2[4 * h + 3] = make_float2(sm_w2[2 * ca + 1] - sm_w2[2 * ca],
                                         sm_w2[2 * cb + 1] - sm_w2[2 * cb]);
        }
    }
    __syncthreads();
    const int f0 = kh * 64;
    // layer 1, K-half kh
    double acc0 = (kh == 0) ? (double)b1[h] : 0.0;
    double acc1 = acc0;
    for (int f = f0; f < f0 + 64; ++f) {
        double w = (double)w1[f * HH + h];        // coalesced across h
        acc0 = fma((double)Xs[0][f], w, acc0);
        acc1 = fma((double)Xs[1][f], w, acc1);
    }
    Hp[kh][0][h] = acc0; Hp[kh][1][h] = acc1;
    __syncthreads();
    if (kh == 0) {
        double v0 = Hp[0][0][h] + Hp[1][0][h];
        double v1 = Hp[0][1][h] + Hp[1][1][h];
        Hs[0][h] = v0 > 0.0 ? v0 : 0.0;
        Hs[1][h] = v1 > 0.0 ? v1 : 0.0;
    }
    __syncthreads();
    // layer 2, K-half kh
    acc0 = (kh == 0) ? (double)b2[h] : 0.0;
    acc1 = acc0;
    for (int c = f0; c < f0 + 64; ++c) {
        double w = (double)w2[c * HH + h];
        acc0 = fma(Hs[0][c], w, acc0);
        acc1 = fma(Hs[1][c], w, acc1);
    }
    Hp[kh][0][h] = acc0; Hp[kh][1][h] = acc1;
    __syncthreads();
    if (kh == 0) {
        const double gate = (double)gatep[0];
        const int k = h & 1, d = h >> 1;
        const int b = row0 / NN;
        const int i0 = row0 % NN;
#pragma unroll
        for (int r = 0; r < EROWS; ++r) {
            double a = Hp[0][r][h] + Hp[1][r][h];
            double v = (double)Xs[r][h] + gate * a;
            size_t idx = (((size_t)(b * 2 + k)) * NN + (i0 + r)) * 64 + d;
            Xc[idx]  = v;
            Xcf[idx] = (float)v;
        }
    }
}

// k2: 512 threads per 32x32 tile. Lane-pair slicing (s = tid&1) on the gram
// K-dim (b128 LDS reads, __shfl_xor reduce); EDGE-sliced MLP in PACKED f32
// (v_pk_fma_f32: 2 channels/instr, SGPR-pair weight operands), weights via
// double-buffered batched scalar loads with the first group hoisted above
// the gram so its s_load latency hides there.
__global__ __launch_bounds__(512, 6)
void edge_decide_kernel(const double* __restrict__ Xc,
                        const float* __restrict__ Xcf,
                        const double* __restrict__ wpack,
                        const float2* __restrict__ wq2,
                        const float* __restrict__ sm_b2,
                        const float* __restrict__ gumbel,
                        float* __restrict__ out) {
    __shared__ float  Ai[2][TS][LST];  // 272B rows: 16B-aligned, banks <=2-way (free)
    __shared__ float  Aj[2][TS][LST];
    __shared__ float  As[TS][TS + 1];
    const int b = blockIdx.y;
    const int t = blockIdx.x;
    // decode upper-triangular pair index: t -> (ti, tj), tj >= ti   (T=24)
    int ti = (int)((49.0 - sqrt(2401.0 - 8.0 * (double)t)) * 0.5);
    int base = ti * (49 - ti) / 2;
    if (t < base) { --ti; base = ti * (49 - ti) / 2; }
    else { int nb = (ti + 1) * (48 - ti) / 2; if (t >= nb) { ++ti; base = nb; } }
    const int tj = t - base + ti;
    const int tid = threadIdx.x;
    const int i0 = ti * TS, j0 = tj * TS;

    // stage f32 Xcf tiles (coalesced float4 global reads; 4 loads/thread)
    for (int q = 0; q < 2; ++q) {
        int flat = tid + 512 * q;        // index over (k, r, d4)
        int d4 = flat & 15;              // float4 slot within row (16/row)
        int r  = (flat >> 4) & 31;
        int k  = flat >> 9;
        size_t rowbase = ((size_t)(b * 2 + k)) * NN;
        *(float4*)&Ai[k][r][4 * d4] = *(const float4*)&Xcf[(rowbase + i0 + r) * 64 + 4 * d4];
        *(float4*)&Aj[k][r][4 * d4] = *(const float4*)&Xcf[(rowbase + j0 + r) * 64 + 4 * d4];
    }

    const int s  = tid & 1;          // slice within lane pair
    const int e  = tid >> 1;         // edge-quad id 0..255
    const int rh = e >> 4;           // 0..15
    const int ch = e & 15;           // 0..15
    const int r0 = rh, r1 = rh + 16;
    const int c0 = 2 * ch, c1 = c0 + 1;
    const int lr  = (s == 0) ? r0 : r1;     // lane-owned local row
    const int gr  = i0 + lr;                // lane-owned global row
    const int gj0 = j0 + c0, gj1 = j0 + c1;

    // per-lane gumbel load (early); first MLP weight group hoisted here too so
    // its uniform s_loads complete under the gram phase.
    float4 gv = *(const float4*)&gumbel[(((size_t)b * NN + gr) * NN + gj0) * 2];
    const v2f* wq = (const v2f*)wq2;    // 4 v2f per channel-pair, 64 pairs
    v2f wA[16], wB[16];                 // 4 pairs (8 channels) per buffer
#pragma unroll
    for (int u = 0; u < 16; ++u) wA[u] = wq[u];
    __syncthreads();

    // f32 gram, K-sliced via b128 reads: slice s covers float4 idx s+2*it
    float p000 = 0.f, p001 = 0.f, p010 = 0.f, p011 = 0.f;
    float p100 = 0.f, p101 = 0.f, p110 = 0.f, p111 = 0.f;
#pragma unroll
    for (int it = 0; it < 8; ++it) {
        const int d4 = (s + 2 * it) * 4;    // float offset of the float4
        float4 a00 = *(const float4*)&Ai[0][r0][d4];
        float4 a01 = *(const float4*)&Ai[0][r1][d4];
        float4 a10 = *(const float4*)&Ai[1][r0][d4];
        float4 a11 = *(const float4*)&Ai[1][r1][d4];
        float4 b00 = *(const float4*)&Aj[0][c0][d4];
        float4 b01 = *(const float4*)&Aj[0][c1][d4];
        float4 b10 = *(const float4*)&Aj[1][c0][d4];
        float4 b11 = *(const float4*)&Aj[1][c1][d4];
        p000 = fmaf(a00.w, b00.w, fmaf(a00.z, b00.z, fmaf(a00.y, b00.y, fmaf(a00.x, b00.x, p000))));
        p001 = fmaf(a00.w, b01.w, fmaf(a00.z, b01.z, fmaf(a00.y, b01.y, fmaf(a00.x, b01.x, p001))));
        p010 = fmaf(a01.w, b00.w, fmaf(a01.z, b00.z, fmaf(a01.y, b00.y, fmaf(a01.x, b00.x, p010))));
        p011 = fmaf(a01.w, b01.w, fmaf(a01.z, b01.z, fmaf(a01.y, b01.y, fmaf(a01.x, b01.x, p011))));
        p100 = fmaf(a10.w, b10.w, fmaf(a10.z, b10.z, fmaf(a10.y, b10.y, fmaf(a10.x, b10.x, p100))));
        p101 = fmaf(a10.w, b11.w, fmaf(a10.z, b11.z, fmaf(a10.y, b11.y, fmaf(a10.x, b11.x, p101))));
        p110 = fmaf(a11.w, b10.w, fmaf(a11.z, b10.z, fmaf(a11.y, b10.y, fmaf(a11.x, b10.x, p110))));
        p111 = fmaf(a11.w, b11.w, fmaf(a11.z, b11.z, fmaf(a11.y, b11.y, fmaf(a11.x, b11.x, p111))));
    }
    // butterfly-reduce p over the lane pair; both lanes get the full dots
    p000 += __shfl_xor(p000, 1); p001 += __shfl_xor(p001, 1);
    p010 += __shfl_xor(p010, 1); p011 += __shfl_xor(p011, 1);
    p100 += __shfl_xor(p100, 1); p101 += __shfl_xor(p101, 1);
    p110 += __shfl_xor(p110, 1); p111 += __shfl_xor(p111, 1);

    // lane-owned edges: (lr, c0) and (lr, c1)
    const float pa0 = (s == 0) ? p000 : p010;   // k0, col c0
    const float pa1 = (s == 0) ? p100 : p110;   // k1, col c0
    const float pb0 = (s == 0) ? p001 : p011;   // k0, col c1
    const float pb1 = (s == 0) ? p101 : p111;   // k1, col c1

    // PACKED f32 edge MLP: 2 channels per v_pk instr. Per channel-pair, per edge:
    // t2 = pk_fma(p0, a2, beta2); t2 = pk_fma(p1, b2, t2); t2 = pk_max(t2, 0);
    // m2 = pk_fma(t2, wd2, m2).  512 packed instrs vs 1024 scalar.
    const v2f q0a = {pa0, pa0}, q1a = {pa1, pa1};
    const v2f q0b = {pb0, pb0}, q1b = {pb1, pb1};
    const v2f z2  = {0.f, 0.f};
    v2f ma2 = {0.f, 0.f}, mb2 = {0.f, 0.f};
#pragma unroll 1
    for (int cg = 0; cg < 8; ++cg) {
        const v2f* nxt1 = wq + (32 * cg + 16);
#pragma unroll
        for (int u = 0; u < 16; ++u) wB[u] = nxt1[u];
#pragma unroll
        for (int pq = 0; pq < 4; ++pq) {
            v2f tt;
            tt  = __builtin_elementwise_fma(q0a, wA[4 * pq + 0], wA[4 * pq + 2]);
            tt  = __builtin_elementwise_fma(q1a, wA[4 * pq + 1], tt);
            tt  = __builtin_elementwise_max(tt, z2);
            ma2 = __builtin_elementwise_fma(tt, wA[4 * pq + 3], ma2);
            tt  = __builtin_elementwise_fma(q0b, wA[4 * pq + 0], wA[4 * pq + 2]);
            tt  = __builtin_elementwise_fma(q1b, wA[4 * pq + 1], tt);
            tt  = __builtin_elementwise_max(tt, z2);
            mb2 = __builtin_elementwise_fma(tt, wA[4 * pq + 3], mb2);
        }
        const v2f* nxt2 = wq + ((cg < 7) ? (32 * cg + 32) : 0);
#pragma unroll
        for (int u = 0; u < 16; ++u) wA[u] = nxt2[u];
#pragma unroll
        for (int pq = 0; pq < 4; ++pq) {
            v2f tt;
            tt  = __builtin_elementwise_fma(q0a, wB[4 * pq + 0], wB[4 * pq + 2]);
            tt  = __builtin_elementwise_fma(q1a, wB[4 * pq + 1], tt);
            tt  = __builtin_elementwise_max(tt, z2);
            ma2 = __builtin_elementwise_fma(tt, wB[4 * pq + 3], ma2);
            tt  = __builtin_elementwise_fma(q0b, wB[4 * pq + 0], wB[4 * pq + 2]);
            tt  = __builtin_elementwise_fma(q1b, wB[4 * pq + 1], tt);
            tt  = __builtin_elementwise_max(tt, z2);
            mb2 = __builtin_elementwise_fma(tt, wB[4 * pq + 3], mb2);
        }
    }
    float ma = ma2.x + ma2.y;
    float mb = mb2.x + mb2.y;

    // decision per lane (2 edges), rare exact-f64 re-decide
    const double bd = (double)sm_b2[1] - (double)sm_b2[0];
    double ia = bd + ((double)gv.y - (double)gv.x);
    double ib = bd + ((double)gv.w - (double)gv.z);
    float fa = ma + (float)ia;
    float fb = mb + (float)ib;
    float Aa = fa > 0.f ? 1.f : 0.f;
    float Ab = fb > 0.f ? 1.f : 0.f;
    if (__builtin_expect(fminf(fabsf(fa), fabsf(fb)) < THR, 0)) {
        if (fabsf(fa) < THR) Aa = edge_exact_f64(Xc, wpack, b, gr, gj0, ia) > 0.0 ? 1.f : 0.f;
        if (fabsf(fb) < THR) Ab = edge_exact_f64(Xc, wpack, b, gr, gj1, ib) > 0.0 ? 1.f : 0.f;
    }
    As[lr][c0] = Aa; As[lr][c1] = Ab;
    __syncthreads();

    if (ti != tj) {
        // direct tile: each lane writes its own row pair (i<j guaranteed)
        *(float2*)&out[((size_t)b * NN + gr) * NN + gj0] = make_float2(Aa, Ab);
        // transposed tile: row j0+lr, cols i0+c0..c1
        float2 tv = make_float2(As[c0][lr], As[c1][lr]);
        *(float2*)&out[((size_t)b * NN + j0 + lr) * NN + i0 + c0] = tv;
    } else {
        // diagonal tile: upper value mirrored, diag = 0
        float v0 = (lr < c0) ? Aa : ((lr > c0) ? As[c0][lr] : 0.0f);
        float v1 = (lr < c1) ? Ab : ((lr > c1) ? As[c1][lr] : 0.0f);
        *(float2*)&out[((size_t)b * NN + gr) * NN + gj0] = make_float2(v0, v1);
    }
}

extern "C" void kernel_launch(void* const* d_in, const int* in_sizes, int n_in,
                              void* d_out, int out_size, void* d_ws, size_t ws_size,
                              hipStream_t stream) {
    const float* X      = (const float*)d_in[0];
    const float* ef_w1  = (const float*)d_in[1];
    const float* ef_b1  = (const float*)d_in[2];
    const float* ef_w2  = (const float*)d_in[3];
    const float* ef_b2  = (const float*)d_in[4];
    const float* gate   = (const float*)d_in[5];
    const float* sm_w1  = (const float*)d_in[6];
    const float* sm_b1  = (const float*)d_in[7];
    const float* sm_w2  = (const float*)d_in[8];
    const float* sm_b2  = (const float*)d_in[9];
    const float* gumbel = (const float*)d_in[10];
    float* out = (float*)d_out;

    double* Xc     = (double*)d_ws;                         // 2*2*768*64 doubles = 1.5 MiB
    double* wpack  = Xc + (size_t)BB * 2 * NN * 64;         // 512 doubles
    float*  Xcf    = (float*)(wpack + 4 * HH);              // 768 KiB f32 copy
    float2* wq2    = (float2*)(Xcf + (size_t)BB * 2 * NN * 64);  // 256 float2 (2 KiB)

    edgefeat_kernel<<<BB * NN / EROWS, 256, 0, stream>>>(
        X, ef_w1, ef_b1, ef_w2, ef_b2, gate, sm_w1, sm_b1, sm_w2, Xc, Xcf, wpack, wq2);
    dim3 grid(NPAIR, BB);
    edge_decide_kernel<<<grid, 512, 0, stream>>>(Xc, Xcf, wpack, wq2, sm_b2, gumbel, out);
}